// Round 15
// baseline (161.874 us; speedup 1.0000x reference)
//
#include <hip/hip_runtime.h>

#define D_IN   2304
#define D_SAE  2048
#define TL     24            // T*L
#define BATCH  32
#define K_TOP  128
#define NLAT   (TL * D_SAE)  // 49152
#define NBIN   8192
#define CAP    2048
#define KSPLIT 2
#define KS     (D_IN / KSPLIT)  // 1152
#define BK     32
#define NCH    (KS / BK)        // 36
#define TOPK_T 512

typedef __attribute__((ext_vector_type(8))) short short8;
typedef __attribute__((ext_vector_type(4))) float f32x4;

// split 8 fp32 into bf16 hi (truncated) + bf16 lo (residual, truncated)
__device__ __forceinline__ void cvt8(const float* f, short8& hi, short8& lo) {
#pragma unroll
    for (int j = 0; j < 8; ++j) {
        unsigned u = __float_as_uint(f[j]);
        hi[j] = (short)(u >> 16);
        float l = f[j] - __uint_as_float(u & 0xFFFF0000u);
        lo[j] = (short)(__float_as_uint(l) >> 16);
    }
}
__device__ __forceinline__ void cvt44(float4 a, float4 b, short8& hi, short8& lo) {
    float f[8];
    *(float4*)&f[0] = a; *(float4*)&f[4] = b;
    cvt8(f, hi, lo);
}

// ---------------- encode: bf16x3 MFMA, LDS-free, barrier-free ----------------
// grid (16, TL, KSPLIT), block 256 (4 waves). Block tile 32 batches x 128 cols;
// wave tile 32x32. W has NO cross-wave reuse -> load B-fragments straight from
// global: per (j,nt)-instruction the 64 lanes touch 4 x 64B contiguous strips
// (full granules, perfectly coalesced). x A-fragments direct to regs (r10).
// Depth-2 prefetch in named reg sets; compiler emits per-set counted vmcnt.
// No LDS, no barriers -> waves free-run; 16 waves/CU.
__global__ __launch_bounds__(256, 2) void enc_kernel(const float* __restrict__ x,
                                                     const float* __restrict__ W,
                                                     float* __restrict__ part) {
    const int tid  = threadIdx.x;
    const int lane = tid & 63;
    const int wv   = tid >> 6;
    const int m0   = lane & 15;         // MFMA row (batch) / col within 16-tile
    const int kb   = lane >> 4;         // K-block (8 elems)
    const int tl   = blockIdx.y;
    const int ks   = blockIdx.z;
    const int col0 = blockIdx.x * 128;

    // lane's W element (ch, j, nt): Wl[((ch)*BK + j)*D_SAE + nt*16]
    const float* Wl = W + ((size_t)(tl * D_IN + ks * KS) + kb * 8) * D_SAE
                    + col0 + wv * 32 + m0;
    const float* xsrc0 = x + ((size_t)(m0 * TL + tl)) * D_IN + ks * KS + kb * 8;
    const float* xsrc1 = x + ((size_t)((16 + m0) * TL + tl)) * D_IN + ks * KS + kb * 8;

    float  wA[16], wB[16];              // B-fragment staging (literal-indexed)
    float4 xA[4],  xB[4];               // A-fragment staging

#define LOADG(S, CH)                                                            \
    do {                                                                        \
        const float* Wc = Wl + (size_t)(CH) * BK * D_SAE;                       \
        _Pragma("unroll")                                                       \
        for (int j = 0; j < 8; ++j) {                                           \
            w##S[j]     = Wc[(size_t)j * D_SAE];                                \
            w##S[8 + j] = Wc[(size_t)j * D_SAE + 16];                           \
        }                                                                       \
        x##S[0] = *(const float4*)(xsrc0 + (CH) * BK);                          \
        x##S[1] = *(const float4*)(xsrc0 + (CH) * BK + 4);                      \
        x##S[2] = *(const float4*)(xsrc1 + (CH) * BK);                          \
        x##S[3] = *(const float4*)(xsrc1 + (CH) * BK + 4);                      \
    } while (0)

    f32x4 acc[2][2];
#pragma unroll
    for (int mt = 0; mt < 2; ++mt)
#pragma unroll
        for (int nt = 0; nt < 2; ++nt) acc[mt][nt] = (f32x4)(0.f);

#define COMPUTE(S)                                                              \
    do {                                                                        \
        short8 a0h, a0l, a1h, a1l, b0h, b0l, b1h, b1l;                          \
        cvt44(x##S[0], x##S[1], a0h, a0l);                                      \
        cvt44(x##S[2], x##S[3], a1h, a1l);                                      \
        cvt8(&w##S[0], b0h, b0l);                                               \
        cvt8(&w##S[8], b1h, b1l);                                               \
        acc[0][0] = __builtin_amdgcn_mfma_f32_16x16x32_bf16(a0h, b0h, acc[0][0], 0, 0, 0); \
        acc[0][0] = __builtin_amdgcn_mfma_f32_16x16x32_bf16(a0h, b0l, acc[0][0], 0, 0, 0); \
        acc[0][0] = __builtin_amdgcn_mfma_f32_16x16x32_bf16(a0l, b0h, acc[0][0], 0, 0, 0); \
        acc[1][0] = __builtin_amdgcn_mfma_f32_16x16x32_bf16(a1h, b0h, acc[1][0], 0, 0, 0); \
        acc[1][0] = __builtin_amdgcn_mfma_f32_16x16x32_bf16(a1h, b0l, acc[1][0], 0, 0, 0); \
        acc[1][0] = __builtin_amdgcn_mfma_f32_16x16x32_bf16(a1l, b0h, acc[1][0], 0, 0, 0); \
        acc[0][1] = __builtin_amdgcn_mfma_f32_16x16x32_bf16(a0h, b1h, acc[0][1], 0, 0, 0); \
        acc[0][1] = __builtin_amdgcn_mfma_f32_16x16x32_bf16(a0h, b1l, acc[0][1], 0, 0, 0); \
        acc[0][1] = __builtin_amdgcn_mfma_f32_16x16x32_bf16(a0l, b1h, acc[0][1], 0, 0, 0); \
        acc[1][1] = __builtin_amdgcn_mfma_f32_16x16x32_bf16(a1h, b1h, acc[1][1], 0, 0, 0); \
        acc[1][1] = __builtin_amdgcn_mfma_f32_16x16x32_bf16(a1h, b1l, acc[1][1], 0, 0, 0); \
        acc[1][1] = __builtin_amdgcn_mfma_f32_16x16x32_bf16(a1l, b1h, acc[1][1], 0, 0, 0); \
    } while (0)

    LOADG(A, 0);
    LOADG(B, 1);
    for (int ch = 0; ch < NCH; ch += 2) {   // NCH = 36, even
        COMPUTE(A);                          // waits only set A's loads
        if (ch + 2 < NCH) LOADG(A, ch + 2);  // refill A while B still in flight
        COMPUTE(B);
        if (ch + 3 < NCH) LOADG(B, ch + 3);
    }
#undef COMPUTE
#undef LOADG

    // C layout (m89-verified): row(batch) = mt*16 + kb*4 + r, col = nt*16 + m0
    float* pp = part + ((size_t)ks * BATCH) * NLAT + (size_t)tl * D_SAE + col0;
#pragma unroll
    for (int mt = 0; mt < 2; ++mt)
#pragma unroll
        for (int nt = 0; nt < 2; ++nt)
#pragma unroll
            for (int r = 0; r < 4; ++r)
                pp[(size_t)(mt * 16 + kb * 4 + r) * NLAT + wv * 32 + nt * 16 + m0] =
                    acc[mt][nt][r];
}

// ------- reduce partials + bias -> pre; zero z (full-chip BW) + loss ----------
__global__ void reduce_kernel(const float* __restrict__ part,
                              const float* __restrict__ b_enc,
                              float* __restrict__ pre,
                              float* __restrict__ z,
                              float* __restrict__ loss) {
    int i = (blockIdx.x * blockDim.x + threadIdx.x) * 4;   // [0, BATCH*NLAT)
    const size_t S = (size_t)BATCH * NLAT;
    float4 v = *(const float4*)&b_enc[i & (D_SAE - 1)];
#pragma unroll
    for (int s = 0; s < KSPLIT; s++) {
        float4 p = *(const float4*)&part[i + s * S];
        v.x += p.x; v.y += p.y; v.z += p.z; v.w += p.w;
    }
    *(float4*)&pre[i] = v;
    z[i] = 0.f; z[i + 1] = 0.f; z[i + 2] = 0.f; z[i + 3] = 0.f;  // z only 4B-aligned
    if (i == 0) *loss = 0.f;
}

// -------- topk: LDS hist + parallel suffix scan; winners only (r14-proven) -----
__global__ __launch_bounds__(TOPK_T) void topk_kernel(const float* __restrict__ pre,
                                                      int* __restrict__ sel_idx,
                                                      float* __restrict__ sel_val,
                                                      float* __restrict__ z) {
    const int b   = blockIdx.x;
    const int tid = threadIdx.x;
    __shared__ unsigned hist[NBIN];
    __shared__ unsigned cand_key[CAP];
    __shared__ int      cand_idx[CAP];
    __shared__ unsigned tsum[TOPK_T];
    __shared__ unsigned scan[TOPK_T];
    __shared__ int s_T, s_hi, s_ccnt, s_sel;

    const float* row  = pre + (size_t)b * NLAT;
    float*       zrow = z   + (size_t)b * NLAT;
    for (int i = tid; i < NBIN; i += TOPK_T) hist[i] = 0;
    if (tid == 0) { s_ccnt = 0; s_sel = 0; }
    __syncthreads();

    for (int i = 4 * tid; i < NLAT; i += 4 * TOPK_T) {
        float4 v = *(const float4*)&row[i];
#pragma unroll
        for (int j = 0; j < 4; j++) {
            unsigned u   = __float_as_uint(((const float*)&v)[j]);
            unsigned key = u ^ ((u >> 31) ? 0xFFFFFFFFu : 0x80000000u); // monotone
            atomicAdd(&hist[key >> 19], 1u);
        }
    }
    __syncthreads();

    unsigned local = 0;
    const int base = tid * (NBIN / TOPK_T);
#pragma unroll
    for (int j = 0; j < NBIN / TOPK_T; j++) local += hist[base + j];
    tsum[tid] = local;
    scan[tid] = local;
    __syncthreads();
    for (int d = 1; d < TOPK_T; d <<= 1) {          // suffix-inclusive scan, 9 steps
        unsigned v = scan[tid] + ((tid + d < TOPK_T) ? scan[tid + d] : 0u);
        __syncthreads();
        scan[tid] = v;
        __syncthreads();
    }
    const unsigned suf_e = scan[tid] - tsum[tid];   // suffix-exclusive
    if (suf_e < K_TOP && suf_e + tsum[tid] >= K_TOP) {   // exactly one thread
        unsigned c = suf_e;
        for (int j = NBIN / TOPK_T - 1; j >= 0; j--) {
            int bin = base + j;
            if (c + hist[bin] >= K_TOP) { s_T = bin; s_hi = (int)c; break; }
            c += hist[bin];
        }
    }
    __syncthreads();

    const int T = s_T;
    for (int i = 4 * tid; i < NLAT; i += 4 * TOPK_T) {
        float4 v = *(const float4*)&row[i];
#pragma unroll
        for (int j = 0; j < 4; j++) {
            float f      = ((const float*)&v)[j];
            unsigned u   = __float_as_uint(f);
            unsigned key = u ^ ((u >> 31) ? 0xFFFFFFFFu : 0x80000000u);
            int bin      = (int)(key >> 19);
            if (bin > T) {                 // winners only; z pre-zeroed in reduce
                int p = atomicAdd(&s_sel, 1);
                float rl = fmaxf(f, 0.f);
                sel_idx[b * K_TOP + p] = i + j;
                sel_val[b * K_TOP + p] = rl;
                zrow[i + j] = rl;
            } else if (bin == T) {
                int p = atomicAdd(&s_ccnt, 1);
                if (p < CAP) { cand_key[p] = key; cand_idx[p] = i + j; }
            }
        }
    }
    __syncthreads();

    const int need = K_TOP - s_hi;
    const int nc   = min(s_ccnt, CAP);
    for (int c = tid; c < nc; c += TOPK_T) {
        unsigned kc = cand_key[c]; int ic = cand_idx[c];
        int rank = 0;
        for (int j = 0; j < nc; j++) {
            unsigned kj = cand_key[j]; int ij = cand_idx[j];
            rank += (kj > kc) || (kj == kc && ij < ic);   // ties -> lower index wins
        }
        if (rank < need) {
            int p = atomicAdd(&s_sel, 1);
            float rl = fmaxf(row[ic], 0.f);
            sel_idx[b * K_TOP + p] = ic;
            sel_val[b * K_TOP + p] = rl;
            zrow[ic] = rl;
        }
    }
}

// ---------------- sparse decode + x_hat + loss ----------------
__global__ __launch_bounds__(256) void dec_kernel(const float* __restrict__ Wd,
                                                  const float* __restrict__ b_dec,
                                                  const float* __restrict__ x,
                                                  const int* __restrict__ sel_idx,
                                                  const float* __restrict__ sel_val,
                                                  float* __restrict__ xhat,
                                                  float* __restrict__ loss) {
    const int tl = blockIdx.x, b = blockIdx.y, tid = threadIdx.x;
    float acc[9];
#pragma unroll
    for (int r = 0; r < 9; r++) acc[r] = b_dec[tl * D_IN + tid + r * 256];

    __shared__ int   s_idx[K_TOP];
    __shared__ float s_val[K_TOP];
    if (tid < K_TOP) { s_idx[tid] = sel_idx[b * K_TOP + tid];
                       s_val[tid] = sel_val[b * K_TOP + tid]; }
    __syncthreads();

    for (int j = 0; j < K_TOP; j++) {
        int f = s_idx[j];
        if ((f >> 11) == tl) {                 // D_SAE = 2048
            float v = s_val[j];
            const float* wrow = Wd + (size_t)f * D_IN;
#pragma unroll
            for (int r = 0; r < 9; r++)
                acc[r] = fmaf(v, wrow[tid + r * 256], acc[r]);
        }
    }

    const float* xr = x    + ((size_t)b * TL + tl) * D_IN;
    float*       xo = xhat + ((size_t)b * TL + tl) * D_IN;
    float lsum = 0.f;
#pragma unroll
    for (int r = 0; r < 9; r++) {
        float d = acc[r] - xr[tid + r * 256];
        xo[tid + r * 256] = acc[r];
        lsum += d * d;
    }
    __shared__ float red[256];
    red[tid] = lsum; __syncthreads();
    for (int s = 128; s > 0; s >>= 1) {
        if (tid < s) red[tid] += red[tid + s];
        __syncthreads();
    }
    if (tid == 0) atomicAdd(loss, red[0] * (1.0f / (BATCH * TL)));
}

extern "C" void kernel_launch(void* const* d_in, const int* in_sizes, int n_in,
                              void* d_out, int out_size, void* d_ws, size_t ws_size,
                              hipStream_t stream) {
    const float* x     = (const float*)d_in[0];
    const float* W_enc = (const float*)d_in[1];
    const float* W_dec = (const float*)d_in[2];
    const float* b_enc = (const float*)d_in[3];
    const float* b_dec = (const float*)d_in[4];

    float* out  = (float*)d_out;
    float* loss = out;
    float* xhat = out + 1;
    float* z    = out + 1 + (size_t)BATCH * TL * D_IN;

    const size_t S = (size_t)BATCH * NLAT;
    float* part    = (float*)d_ws;
    float* pre     = part + (size_t)KSPLIT * S;
    int*   sel_idx = (int*)(pre + S);
    float* sel_val = (float*)(sel_idx + BATCH * K_TOP);

    enc_kernel<<<dim3(16, TL, KSPLIT), 256, 0, stream>>>(x, W_enc, part);
    reduce_kernel<<<(int)(S / 1024), 256, 0, stream>>>(part, b_enc, pre, z, loss);
    topk_kernel<<<BATCH, TOPK_T, 0, stream>>>(pre, sel_idx, sel_val, z);
    dec_kernel<<<dim3(TL, BATCH), 256, 0, stream>>>(W_dec, b_dec, x, sel_idx, sel_val,
                                                    xhat, loss);
}